// Round 19
// baseline (162.554 us; speedup 1.0000x reference)
//
#include <hip/hip_runtime.h>

typedef unsigned short u16;
typedef unsigned int u32;
typedef __attribute__((ext_vector_type(4))) u16 u16x4;
typedef __attribute__((ext_vector_type(8))) short short8;
typedef __attribute__((ext_vector_type(4))) float f32x4;
typedef __attribute__((ext_vector_type(16))) float f32x16;
typedef __attribute__((ext_vector_type(4))) u32 uint4v;

#define AS1 __attribute__((address_space(1)))
#define AS3 __attribute__((address_space(3)))

#define B_  4
#define S_  2048
#define D_  1024
#define H_  16
#define DK_ 64

#define WAIT_VM(n) asm volatile("s_waitcnt vmcnt(" #n ")" ::: "memory")
#define WAIT_LGK0  asm volatile("s_waitcnt lgkmcnt(0)" ::: "memory")

__device__ __forceinline__ u16 f2bf(float f) {
  union { float f; unsigned u; } v; v.f = f;
  unsigned r = v.u + 0x7fffu + ((v.u >> 16) & 1u);
  return (u16)(r >> 16);
}

__device__ __forceinline__ u32 cvt_pk_bf16(float lo, float hi) {
  u32 r;
  asm("v_cvt_pk_bf16_f32 %0, %1, %2" : "=v"(r) : "v"(lo), "v"(hi));
  return r;
}

__device__ __forceinline__ void pl32_swap(u32& a, u32& b) {
  asm("v_permlane32_swap_b32 %0, %1" : "+v"(a), "+v"(b));
}

__device__ __forceinline__ void gload_lds16(const void* g, void* l) {
  __builtin_amdgcn_global_load_lds((const AS1 void*)g, (AS3 void*)l, 16, 0, 0);
}

// ------------- fused fp32 -> bf16 convert: x (4096 blks) + 4 weights -------
__global__ __launch_bounds__(256) void conv_all(const float* __restrict__ x,
                                                const float* __restrict__ w0,
                                                const float* __restrict__ w1,
                                                const float* __restrict__ w2,
                                                const float* __restrict__ w3,
                                                u16* __restrict__ xb,
                                                u16* __restrict__ wout,
                                                float s0) {
  int bid = blockIdx.x;
  const float* src;
  u16* dst;
  float scale = 1.0f;
  int i;
  if (bid < 4096) {               // x: 8388608 elems
    src = x; dst = xb;
    i = bid * 2048 + threadIdx.x * 8;
  } else {                        // weights: 4 x 1048576 elems, 512 blocks each
    int widx = bid - 4096;
    int y = widx >> 9;
    src = (y == 0) ? w0 : (y == 1) ? w1 : (y == 2) ? w2 : w3;
    if (y == 0) scale = s0;
    dst = wout + (size_t)y * (D_ * D_);
    i = (widx & 511) * 2048 + threadIdx.x * 8;
  }
  f32x4 a = *reinterpret_cast<const f32x4*>(src + i);
  f32x4 b = *reinterpret_cast<const f32x4*>(src + i + 4);
  union { u16 u[8]; uint4v v; } r;
#pragma unroll
  for (int j = 0; j < 4; ++j) {
    r.u[j]     = f2bf(a[j] * scale);
    r.u[4 + j] = f2bf(b[j] * scale);
  }
  *reinterpret_cast<uint4v*>(dst + i) = r.v;
}

// ---------------- GEMM: C[M,N] = A[M,K] * B[N,K]^T (R14-proven pipeline) ---
// 128² tile, BK=64, double-buffered 64 KiB LDS (2 blocks/CU).
// MODE 0 (QKV): L2-blocked XCD mapping — XCD x owns m-panels [8x,8x+8) for
// all N. MODE 1 (O-proj): row-major XCD-chunk mapping.
template<int MODE>
__global__ __launch_bounds__(256) void gemm_bt(const u16* __restrict__ A,
                                               const u16* __restrict__ B,
                                               u16* __restrict__ Qb,
                                               u16* __restrict__ Kb,
                                               u16* __restrict__ Vt,
                                               float* __restrict__ Cf,
                                               const float* __restrict__ bias,
                                               int M, int N, int K, int nbx) {
  __shared__ __attribute__((aligned(16))) u16 As[2][128 * 64];
  __shared__ __attribute__((aligned(16))) u16 Bs[2][128 * 64];

  const int t = threadIdx.x;
  const int l = t & 63;
  const int w = t >> 6;
  const int wr = w >> 1, wc = w & 1;
  const int dd = blockIdx.x;
  int m0, n0;
  if (MODE == 0) {
    const int xcd = dd & 7;
    const int j = dd >> 3;              // 0..191
    m0 = (xcd * 8 + (j & 7)) * 128;     // A-panel fixed per XCD window
    n0 = (j >> 3) * 128;                // B-panel slides n-major
  } else {
    const int cpx = gridDim.x >> 3;
    const int lid = (dd & 7) * cpx + (dd >> 3);
    m0 = (lid / nbx) * 128;
    n0 = (lid % nbx) * 128;
  }
  const int NT = K >> 6;

  f32x4 zero = {0.f, 0.f, 0.f, 0.f};
  f32x4 acc[4][4];
#pragma unroll
  for (int i = 0; i < 4; ++i)
#pragma unroll
    for (int j = 0; j < 4; ++j) acc[i][j] = zero;

  auto stage = [&](int kt, int buf) {
#pragma unroll
    for (int i = 0; i < 4; ++i) {
      int slot = i * 256 + t;
      int r = slot >> 3, c = slot & 7;
      gload_lds16(A + (size_t)(m0 + r) * K + kt * 64 + ((c ^ (r & 7)) * 8),
                  (char*)&As[buf][0] + (size_t)(i * 256 + w * 64) * 16);
      gload_lds16(B + (size_t)(n0 + r) * K + kt * 64 + ((c ^ (r & 7)) * 8),
                  (char*)&Bs[buf][0] + (size_t)(i * 256 + w * 64) * 16);
    }
  };

  stage(0, 0);
  stage(1, 1);

  for (int kt = 0; kt < NT; ++kt) {
    const int buf = kt & 1;
    if (kt < NT - 1) { WAIT_VM(8); } else { WAIT_VM(0); }
    __builtin_amdgcn_s_barrier();
    __builtin_amdgcn_sched_barrier(0);

#pragma unroll
    for (int kc = 0; kc < 2; ++kc) {
      short8 a[4], bf[4];
      int lc = kc * 4 + (l >> 4);
#pragma unroll
      for (int i = 0; i < 4; ++i) {
        int ra = wr * 64 + i * 16 + (l & 15);
        a[i] = *reinterpret_cast<const short8*>(&As[buf][ra * 64 + ((lc ^ (ra & 7)) * 8)]);
        int rb = wc * 64 + i * 16 + (l & 15);
        bf[i] = *reinterpret_cast<const short8*>(&Bs[buf][rb * 64 + ((lc ^ (rb & 7)) * 8)]);
      }
#pragma unroll
      for (int mi = 0; mi < 4; ++mi)
#pragma unroll
        for (int ni = 0; ni < 4; ++ni)
          acc[mi][ni] = __builtin_amdgcn_mfma_f32_16x16x32_bf16(a[mi], bf[ni], acc[mi][ni], 0, 0, 0);
    }

    WAIT_LGK0;
    __builtin_amdgcn_sched_barrier(0);
    __builtin_amdgcn_s_barrier();
    if (kt + 2 < NT) stage(kt + 2, buf);
  }

#pragma unroll
  for (int ni = 0; ni < 4; ++ni) {
    int col = n0 + wc * 64 + ni * 16 + (l & 15);
    float bv = (MODE == 1) ? bias[col] : 0.f;
#pragma unroll
    for (int mi = 0; mi < 4; ++mi) {
      int row0 = m0 + wr * 64 + mi * 16 + (l >> 4) * 4;
      if (MODE == 1) {
#pragma unroll
        for (int r = 0; r < 4; ++r)
          Cf[(size_t)(row0 + r) * N + col] = acc[mi][ni][r] + bv;
      } else {
        if (col < 2048) {
          u16* dst = (col < 1024) ? Qb : Kb;
          int c = col & 1023;
#pragma unroll
          for (int r = 0; r < 4; ++r)
            dst[(size_t)(row0 + r) * 1024 + c] = f2bf(acc[mi][ni][r]);
        } else {
          int vc = col - 2048;
          int bh = (row0 >> 11) * 16 + (vc >> 6);
          int s0 = row0 & 2047;
          u16x4 pk;
#pragma unroll
          for (int r = 0; r < 4; ++r) pk[r] = f2bf(acc[mi][ni][r]);
          *reinterpret_cast<u16x4*>(Vt + ((size_t)(bh * 64 + (vc & 63))) * 2048 + s0) = pk;
        }
      }
    }
  }
}

// ---------------- causal flash attention (4-buf + MFMA row-sum) ------------
// grid (B*H, 8): 512 threads = 8 waves x 32 q-rows of a 256-row supertile.
// s-map {7,5,3,1,0,2,4,6}. FOUR K/V buffers, 1 barrier/iter, counted vmcnt.
// No-max softmax. Row-sum l = Σ exp computed ON THE MATRIX PIPE: one extra
// mfma(A=ones, B=P^T) per ksl accumulates Σ_k P[q][k] into o_l — every lane
// gets its own q's total in o_l[0] (all rows of the ones-product identical;
// K=16 covers both half-waves' k-slices, so no cross-half shfl needed).
__global__ __launch_bounds__(512) void attn_fwd(const u16* __restrict__ Q,
                                                const u16* __restrict__ K,
                                                const u16* __restrict__ Vtg,
                                                u16* __restrict__ AO) {
  __shared__ __attribute__((aligned(16))) u16 smem[32768];  // 64 KiB
  u16* Ksb = smem;            // 4 bufs x 4096 u16
  u16* Vsb = smem + 16384;    // 4 bufs x 4096 u16

  const int t = threadIdx.x;
  const int l = t & 63;
  const int w = t >> 6;
  const int hi = l >> 5;
  const int hi8 = hi * 8, hi4 = hi * 4;
  const int bh = blockIdx.x;
  const int by = blockIdx.y;
  const int s = (by < 4) ? (7 - 2 * by) : (2 * (by - 4));
  const size_t qkbase = (size_t)((bh >> 4) * S_) * D_ + (bh & 15) * DK_;
  const u16* Vg = Vtg + (size_t)bh * 64 * S_;

  const int qw = s * 256 + w * 32;
  const int qi = qw + (l & 31);

  short8 qf[4];
#pragma unroll
  for (int c = 0; c < 4; ++c)
    qf[c] = *reinterpret_cast<const short8*>(Q + qkbase + (size_t)qi * D_ + c * 16 + hi8);

  short8 onesf;
#pragma unroll
  for (int i = 0; i < 8; ++i) onesf[i] = (short)0x3F80;  // bf16 1.0

  f32x16 o0 = {0,0,0,0,0,0,0,0,0,0,0,0,0,0,0,0};
  f32x16 o1 = {0,0,0,0,0,0,0,0,0,0,0,0,0,0,0,0};
  f32x16 o_l = {0,0,0,0,0,0,0,0,0,0,0,0,0,0,0,0};

  const int nst = 4 * (s + 1);  // 4..32

  auto stage = [&](int jt, u16* kdst, u16* vdst) {
    const u16* Ksrc = K + qkbase + (size_t)(jt * 64) * D_;
    const u16* Vsrc = Vg + jt * 64;
    int r = t >> 3, c = t & 7;
    gload_lds16(Ksrc + (size_t)r * D_ + ((c ^ (r & 7)) * 8),
                (char*)kdst + (size_t)t * 16);
    gload_lds16(Vsrc + (size_t)r * S_ + ((c ^ (r & 7)) * 8),
                (char*)vdst + (size_t)t * 16);
  };

  stage(0, Ksb, Vsb);
  stage(1, Ksb + 4096, Vsb + 4096);
  stage(2, Ksb + 8192, Vsb + 8192);
  int ob0 = 0, ob1 = 4096, ob2 = 8192, ob3 = 12288;

  for (int it = 0; it < nst; ++it) {
    if (it < nst - 2)       { WAIT_VM(4); }
    else if (it == nst - 2) { WAIT_VM(2); }
    else                    { WAIT_VM(0); }
    __builtin_amdgcn_s_barrier();
    __builtin_amdgcn_sched_barrier(0);
    // stage early: buf ob3's last readers (iter it-1) are past this barrier
    if (it + 3 < nst) stage(it + 3, Ksb + ob3, Vsb + ob3);

    const int j0 = it * 64;
    u16* ks = Ksb + ob0;
    u16* vs = Vsb + ob0;

    if (j0 <= qw + 31) {
      f32x16 s0 = {0,0,0,0,0,0,0,0,0,0,0,0,0,0,0,0};
      f32x16 s1 = {0,0,0,0,0,0,0,0,0,0,0,0,0,0,0,0};
      __builtin_amdgcn_s_setprio(1);
#pragma unroll
      for (int c = 0; c < 4; ++c) {
        int cl = 2 * c + hi;
        int k0r = l & 31, k1r = (l & 31) + 32;
        short8 kf0 = *reinterpret_cast<const short8*>(&ks[k0r * 64 + ((cl ^ (k0r & 7)) * 8)]);
        short8 kf1 = *reinterpret_cast<const short8*>(&ks[k1r * 64 + ((cl ^ (k1r & 7)) * 8)]);
        s0 = __builtin_amdgcn_mfma_f32_32x32x16_bf16(kf0, qf[c], s0, 0, 0, 0);
        s1 = __builtin_amdgcn_mfma_f32_32x32x16_bf16(kf1, qf[c], s1, 0, 0, 0);
      }
      __builtin_amdgcn_s_setprio(0);
      if (j0 + 63 > qw) {
#pragma unroll
        for (int r = 0; r < 16; ++r) {
          int key = j0 + (r & 3) + 8 * (r >> 2) + hi4;
          if (key > qi) s0[r] = -INFINITY;
          if (key + 32 > qi) s1[r] = -INFINITY;
        }
      }
      // softmax without max-tracking: p = exp2(s) only (sum on matrix pipe)
#pragma unroll
      for (int r = 0; r < 16; ++r) {
        s0[r] = __builtin_amdgcn_exp2f(s0[r]);
        s1[r] = __builtin_amdgcn_exp2f(s1[r]);
      }
      // PV (+ ones-MFMA row-sum)
      __builtin_amdgcn_s_setprio(1);
#pragma unroll
      for (int ksl = 0; ksl < 4; ++ksl) {
        const int b = 8 * (ksl & 1);
        const f32x16& ps = (ksl < 2) ? s0 : s1;
        u32 c0 = cvt_pk_bf16(ps[b + 0], ps[b + 1]);
        u32 c1 = cvt_pk_bf16(ps[b + 2], ps[b + 3]);
        u32 c2 = cvt_pk_bf16(ps[b + 4], ps[b + 5]);
        u32 c3 = cvt_pk_bf16(ps[b + 6], ps[b + 7]);
        pl32_swap(c0, c2);
        pl32_swap(c1, c3);
        union { u32 u[4]; short8 s; } pa;
        pa.u[0] = c0; pa.u[1] = c1; pa.u[2] = c2; pa.u[3] = c3;
        int cl = 2 * ksl + hi;
        int d0r = l & 31, d1r = (l & 31) + 32;
        short8 vf0 = *reinterpret_cast<const short8*>(&vs[d0r * 64 + ((cl ^ (d0r & 7)) * 8)]);
        short8 vf1 = *reinterpret_cast<const short8*>(&vs[d1r * 64 + ((cl ^ (d1r & 7)) * 8)]);
        o0 = __builtin_amdgcn_mfma_f32_32x32x16_bf16(vf0, pa.s, o0, 0, 0, 0);
        o1 = __builtin_amdgcn_mfma_f32_32x32x16_bf16(vf1, pa.s, o1, 0, 0, 0);
        o_l = __builtin_amdgcn_mfma_f32_32x32x16_bf16(onesf, pa.s, o_l, 0, 0, 0);
      }
      __builtin_amdgcn_s_setprio(0);
    }

    int tmp = ob0; ob0 = ob1; ob1 = ob2; ob2 = ob3; ob3 = tmp;
  }

  // loop has no trailing barrier; epilogue reuses smem -> sync first
  __syncthreads();

  // epilogue: normalize (l = o_l[0], exact Σ exp for this lane's q), bounce
  // O^T -> row-major via per-wave LDS, 16B stores
  float inv = 1.0f / o_l[0];
  u16* Ob = smem + w * 2304;
#pragma unroll
  for (int acc = 0; acc < 2; ++acc) {
    const f32x16& oo = acc ? o1 : o0;
#pragma unroll
    for (int rp = 0; rp < 8; ++rp) {
      u32 pk = cvt_pk_bf16(oo[2 * rp] * inv, oo[2 * rp + 1] * inv);
      int d0 = ((2 * rp) & 3) + 8 * (rp >> 1) + hi4 + 32 * acc;
      *reinterpret_cast<u32*>(&Ob[(l & 31) * 72 + d0]) = pk;
    }
  }
  __syncthreads();
  int qq = l >> 1;
  int chb = (l & 1) * 4;
#pragma unroll
  for (int c2 = 0; c2 < 4; ++c2) {
    uint4v vv = *reinterpret_cast<const uint4v*>(&Ob[qq * 72 + (chb + c2) * 8]);
    *reinterpret_cast<uint4v*>(&AO[qkbase + (size_t)(qw + qq) * D_ + (chb + c2) * 8]) = vv;
  }
}

// ---------------- launch ----------------
extern "C" void kernel_launch(void* const* d_in, const int* in_sizes, int n_in,
                              void* d_out, int out_size, void* d_ws, size_t ws_size,
                              hipStream_t stream) {
  const float* x  = (const float*)d_in[0];
  const float* wq = (const float*)d_in[1];
  const float* wk = (const float*)d_in[2];
  const float* wv = (const float*)d_in[3];
  const float* wo = (const float*)d_in[4];
  const float* bo = (const float*)d_in[5];
  float* out = (float*)d_out;

  char* ws = (char*)d_ws;
  u16* XB   = (u16*)(ws);                       // 16 MiB
  u16* WQKV = (u16*)(ws + (size_t)(16 << 20));  // 6 MiB (wq|wk|wv), then wo
  u16* WOB  = (u16*)(ws + (size_t)(22 << 20));  // 2 MiB
  u16* Qb   = (u16*)(ws + (size_t)(24 << 20));
  u16* Kb   = (u16*)(ws + (size_t)(40 << 20));
  u16* Vt   = (u16*)(ws + (size_t)(56 << 20));  // [bh*64+d][s]
  u16* AO   = (u16*)(ws + (size_t)(72 << 20));

  // one conversion launch: 4096 x-blocks + 2048 weight-blocks
  // wq scale folds DK^-0.5 * log2(e) for exp2-domain softmax
  conv_all<<<6144, 256, 0, stream>>>(x, wq, wk, wv, wo, XB, WQKV,
                                     0.18033688011112042f);

  // QKV: M=8192, N=3072 -> 1536 blocks of 128² (L2-blocked XCD mapping)
  gemm_bt<0><<<1536, 256, 0, stream>>>(
      XB, WQKV, Qb, Kb, Vt, nullptr, nullptr, B_ * S_, 3072, D_, 24);

  attn_fwd<<<dim3(B_ * H_, 8), 512, 0, stream>>>(Qb, Kb, Vt, AO);

  // O-proj: M=8192, N=1024 -> 512 blocks of 128²
  gemm_bt<1><<<512, 256, 0, stream>>>(
      AO, WOB, nullptr, nullptr, nullptr, out, bo, B_ * S_, D_, D_, 8);
}

// Round 20
// 150.192 us; speedup vs baseline: 1.0823x; 1.0823x over previous
//
#include <hip/hip_runtime.h>

typedef unsigned short u16;
typedef unsigned int u32;
typedef __attribute__((ext_vector_type(4))) u16 u16x4;
typedef __attribute__((ext_vector_type(8))) short short8;
typedef __attribute__((ext_vector_type(4))) float f32x4;
typedef __attribute__((ext_vector_type(16))) float f32x16;
typedef __attribute__((ext_vector_type(4))) u32 uint4v;

#define AS1 __attribute__((address_space(1)))
#define AS3 __attribute__((address_space(3)))

#define B_  4
#define S_  2048
#define D_  1024
#define H_  16
#define DK_ 64

#define WAIT_VM(n) asm volatile("s_waitcnt vmcnt(" #n ")" ::: "memory")
#define WAIT_LGK0  asm volatile("s_waitcnt lgkmcnt(0)" ::: "memory")

__device__ __forceinline__ u16 f2bf(float f) {
  union { float f; unsigned u; } v; v.f = f;
  unsigned r = v.u + 0x7fffu + ((v.u >> 16) & 1u);
  return (u16)(r >> 16);
}

__device__ __forceinline__ u32 cvt_pk_bf16(float lo, float hi) {
  u32 r;
  asm("v_cvt_pk_bf16_f32 %0, %1, %2" : "=v"(r) : "v"(lo), "v"(hi));
  return r;
}

__device__ __forceinline__ void pl32_swap(u32& a, u32& b) {
  asm("v_permlane32_swap_b32 %0, %1" : "+v"(a), "+v"(b));
}

__device__ __forceinline__ void gload_lds16(const void* g, void* l) {
  __builtin_amdgcn_global_load_lds((const AS1 void*)g, (AS3 void*)l, 16, 0, 0);
}

// ------------- fused fp32 -> bf16 convert: x (4096 blks) + 4 weights -------
__global__ __launch_bounds__(256) void conv_all(const float* __restrict__ x,
                                                const float* __restrict__ w0,
                                                const float* __restrict__ w1,
                                                const float* __restrict__ w2,
                                                const float* __restrict__ w3,
                                                u16* __restrict__ xb,
                                                u16* __restrict__ wout,
                                                float s0) {
  int bid = blockIdx.x;
  const float* src;
  u16* dst;
  float scale = 1.0f;
  int i;
  if (bid < 4096) {               // x: 8388608 elems
    src = x; dst = xb;
    i = bid * 2048 + threadIdx.x * 8;
  } else {                        // weights: 4 x 1048576 elems, 512 blocks each
    int widx = bid - 4096;
    int y = widx >> 9;
    src = (y == 0) ? w0 : (y == 1) ? w1 : (y == 2) ? w2 : w3;
    if (y == 0) scale = s0;
    dst = wout + (size_t)y * (D_ * D_);
    i = (widx & 511) * 2048 + threadIdx.x * 8;
  }
  f32x4 a = *reinterpret_cast<const f32x4*>(src + i);
  f32x4 b = *reinterpret_cast<const f32x4*>(src + i + 4);
  union { u16 u[8]; uint4v v; } r;
#pragma unroll
  for (int j = 0; j < 4; ++j) {
    r.u[j]     = f2bf(a[j] * scale);
    r.u[4 + j] = f2bf(b[j] * scale);
  }
  *reinterpret_cast<uint4v*>(dst + i) = r.v;
}

// ---------------- GEMM: C[M,N] = A[M,K] * B[N,K]^T (R14-proven pipeline) ---
// 128² tile, BK=64, double-buffered 64 KiB LDS (2 blocks/CU).
// MODE 0 (QKV): L2-blocked XCD mapping — XCD x owns m-panels [8x,8x+8) for
// all N (A 2MB stays L2-hot; n-major order slides an 8-panel 2MB B window).
// MODE 1 (O-proj): row-major XCD-chunk mapping (working set fits).
template<int MODE>
__global__ __launch_bounds__(256) void gemm_bt(const u16* __restrict__ A,
                                               const u16* __restrict__ B,
                                               u16* __restrict__ Qb,
                                               u16* __restrict__ Kb,
                                               u16* __restrict__ Vt,
                                               float* __restrict__ Cf,
                                               const float* __restrict__ bias,
                                               int M, int N, int K, int nbx) {
  __shared__ __attribute__((aligned(16))) u16 As[2][128 * 64];
  __shared__ __attribute__((aligned(16))) u16 Bs[2][128 * 64];

  const int t = threadIdx.x;
  const int l = t & 63;
  const int w = t >> 6;
  const int wr = w >> 1, wc = w & 1;
  const int dd = blockIdx.x;
  int m0, n0;
  if (MODE == 0) {
    const int xcd = dd & 7;
    const int j = dd >> 3;              // 0..191
    m0 = (xcd * 8 + (j & 7)) * 128;     // A-panel fixed per XCD window
    n0 = (j >> 3) * 128;                // B-panel slides n-major
  } else {
    const int cpx = gridDim.x >> 3;
    const int lid = (dd & 7) * cpx + (dd >> 3);
    m0 = (lid / nbx) * 128;
    n0 = (lid % nbx) * 128;
  }
  const int NT = K >> 6;

  f32x4 zero = {0.f, 0.f, 0.f, 0.f};
  f32x4 acc[4][4];
#pragma unroll
  for (int i = 0; i < 4; ++i)
#pragma unroll
    for (int j = 0; j < 4; ++j) acc[i][j] = zero;

  auto stage = [&](int kt, int buf) {
#pragma unroll
    for (int i = 0; i < 4; ++i) {
      int slot = i * 256 + t;
      int r = slot >> 3, c = slot & 7;
      gload_lds16(A + (size_t)(m0 + r) * K + kt * 64 + ((c ^ (r & 7)) * 8),
                  (char*)&As[buf][0] + (size_t)(i * 256 + w * 64) * 16);
      gload_lds16(B + (size_t)(n0 + r) * K + kt * 64 + ((c ^ (r & 7)) * 8),
                  (char*)&Bs[buf][0] + (size_t)(i * 256 + w * 64) * 16);
    }
  };

  stage(0, 0);
  stage(1, 1);

  for (int kt = 0; kt < NT; ++kt) {
    const int buf = kt & 1;
    if (kt < NT - 1) { WAIT_VM(8); } else { WAIT_VM(0); }
    __builtin_amdgcn_s_barrier();
    __builtin_amdgcn_sched_barrier(0);

#pragma unroll
    for (int kc = 0; kc < 2; ++kc) {
      short8 a[4], bf[4];
      int lc = kc * 4 + (l >> 4);
#pragma unroll
      for (int i = 0; i < 4; ++i) {
        int ra = wr * 64 + i * 16 + (l & 15);
        a[i] = *reinterpret_cast<const short8*>(&As[buf][ra * 64 + ((lc ^ (ra & 7)) * 8)]);
        int rb = wc * 64 + i * 16 + (l & 15);
        bf[i] = *reinterpret_cast<const short8*>(&Bs[buf][rb * 64 + ((lc ^ (rb & 7)) * 8)]);
      }
#pragma unroll
      for (int mi = 0; mi < 4; ++mi)
#pragma unroll
        for (int ni = 0; ni < 4; ++ni)
          acc[mi][ni] = __builtin_amdgcn_mfma_f32_16x16x32_bf16(a[mi], bf[ni], acc[mi][ni], 0, 0, 0);
    }

    WAIT_LGK0;
    __builtin_amdgcn_sched_barrier(0);
    __builtin_amdgcn_s_barrier();
    if (kt + 2 < NT) stage(kt + 2, buf);
  }

#pragma unroll
  for (int ni = 0; ni < 4; ++ni) {
    int col = n0 + wc * 64 + ni * 16 + (l & 15);
    float bv = (MODE == 1) ? bias[col] : 0.f;
#pragma unroll
    for (int mi = 0; mi < 4; ++mi) {
      int row0 = m0 + wr * 64 + mi * 16 + (l >> 4) * 4;
      if (MODE == 1) {
#pragma unroll
        for (int r = 0; r < 4; ++r)
          Cf[(size_t)(row0 + r) * N + col] = acc[mi][ni][r] + bv;
      } else {
        if (col < 2048) {
          u16* dst = (col < 1024) ? Qb : Kb;
          int c = col & 1023;
#pragma unroll
          for (int r = 0; r < 4; ++r)
            dst[(size_t)(row0 + r) * 1024 + c] = f2bf(acc[mi][ni][r]);
        } else {
          int vc = col - 2048;
          int bh = (row0 >> 11) * 16 + (vc >> 6);
          int s0 = row0 & 2047;
          u16x4 pk;
#pragma unroll
          for (int r = 0; r < 4; ++r) pk[r] = f2bf(acc[mi][ni][r]);
          *reinterpret_cast<u16x4*>(Vt + ((size_t)(bh * 64 + (vc & 63))) * 2048 + s0) = pk;
        }
      }
    }
  }
}

// ---------------- causal flash attention (4-buf single-barrier, R18) -------
// grid (B*H, 8): 512 threads = 8 waves x 32 q-rows of a 256-row supertile.
// s-map {7,5,3,1,0,2,4,6}. FOUR K/V buffers: stage(it+3) targets the buffer
// whose last readers (iter it-1) are provably past this iter's acquire
// barrier -> 1 barrier/iter. Counted vmcnt (4/2/0). No-max softmax;
// raw v_exp_f32; pairwise-tree sum.
__global__ __launch_bounds__(512) void attn_fwd(const u16* __restrict__ Q,
                                                const u16* __restrict__ K,
                                                const u16* __restrict__ Vtg,
                                                u16* __restrict__ AO) {
  __shared__ __attribute__((aligned(16))) u16 smem[32768];  // 64 KiB
  u16* Ksb = smem;            // 4 bufs x 4096 u16
  u16* Vsb = smem + 16384;    // 4 bufs x 4096 u16

  const int t = threadIdx.x;
  const int l = t & 63;
  const int w = t >> 6;
  const int hi = l >> 5;
  const int hi8 = hi * 8, hi4 = hi * 4;
  const int bh = blockIdx.x;
  const int by = blockIdx.y;
  const int s = (by < 4) ? (7 - 2 * by) : (2 * (by - 4));
  const size_t qkbase = (size_t)((bh >> 4) * S_) * D_ + (bh & 15) * DK_;
  const u16* Vg = Vtg + (size_t)bh * 64 * S_;

  const int qw = s * 256 + w * 32;
  const int qi = qw + (l & 31);

  short8 qf[4];
#pragma unroll
  for (int c = 0; c < 4; ++c)
    qf[c] = *reinterpret_cast<const short8*>(Q + qkbase + (size_t)qi * D_ + c * 16 + hi8);

  f32x16 o0 = {0,0,0,0,0,0,0,0,0,0,0,0,0,0,0,0};
  f32x16 o1 = {0,0,0,0,0,0,0,0,0,0,0,0,0,0,0,0};
  float l_r = 0.f;

  const int nst = 4 * (s + 1);  // 4..32

  auto stage = [&](int jt, u16* kdst, u16* vdst) {
    const u16* Ksrc = K + qkbase + (size_t)(jt * 64) * D_;
    const u16* Vsrc = Vg + jt * 64;
    int r = t >> 3, c = t & 7;
    gload_lds16(Ksrc + (size_t)r * D_ + ((c ^ (r & 7)) * 8),
                (char*)kdst + (size_t)t * 16);
    gload_lds16(Vsrc + (size_t)r * S_ + ((c ^ (r & 7)) * 8),
                (char*)vdst + (size_t)t * 16);
  };

  stage(0, Ksb, Vsb);
  stage(1, Ksb + 4096, Vsb + 4096);
  stage(2, Ksb + 8192, Vsb + 8192);
  int ob0 = 0, ob1 = 4096, ob2 = 8192, ob3 = 12288;

  for (int it = 0; it < nst; ++it) {
    if (it < nst - 2)       { WAIT_VM(4); }
    else if (it == nst - 2) { WAIT_VM(2); }
    else                    { WAIT_VM(0); }
    __builtin_amdgcn_s_barrier();
    __builtin_amdgcn_sched_barrier(0);
    // stage early: buf ob3's last readers (iter it-1) are past this barrier
    if (it + 3 < nst) stage(it + 3, Ksb + ob3, Vsb + ob3);

    const int j0 = it * 64;
    u16* ks = Ksb + ob0;
    u16* vs = Vsb + ob0;

    if (j0 <= qw + 31) {
      f32x16 s0 = {0,0,0,0,0,0,0,0,0,0,0,0,0,0,0,0};
      f32x16 s1 = {0,0,0,0,0,0,0,0,0,0,0,0,0,0,0,0};
      __builtin_amdgcn_s_setprio(1);
#pragma unroll
      for (int c = 0; c < 4; ++c) {
        int cl = 2 * c + hi;
        int k0r = l & 31, k1r = (l & 31) + 32;
        short8 kf0 = *reinterpret_cast<const short8*>(&ks[k0r * 64 + ((cl ^ (k0r & 7)) * 8)]);
        short8 kf1 = *reinterpret_cast<const short8*>(&ks[k1r * 64 + ((cl ^ (k1r & 7)) * 8)]);
        s0 = __builtin_amdgcn_mfma_f32_32x32x16_bf16(kf0, qf[c], s0, 0, 0, 0);
        s1 = __builtin_amdgcn_mfma_f32_32x32x16_bf16(kf1, qf[c], s1, 0, 0, 0);
      }
      __builtin_amdgcn_s_setprio(0);
      if (j0 + 63 > qw) {
#pragma unroll
        for (int r = 0; r < 16; ++r) {
          int key = j0 + (r & 3) + 8 * (r >> 2) + hi4;
          if (key > qi) s0[r] = -INFINITY;
          if (key + 32 > qi) s1[r] = -INFINITY;
        }
      }
      // softmax without max-tracking: p = exp2(s); pairwise-tree sum
      {
        float p[16];
#pragma unroll
        for (int r = 0; r < 16; ++r) {
          s0[r] = __builtin_amdgcn_exp2f(s0[r]);
          s1[r] = __builtin_amdgcn_exp2f(s1[r]);
          p[r] = s0[r] + s1[r];
        }
#pragma unroll
        for (int st = 8; st > 0; st >>= 1)
#pragma unroll
          for (int r = 0; r < st; ++r) p[r] += p[r + st];
        float sum = p[0];
        sum += __shfl_xor(sum, 32);
        l_r += sum;
      }
      // PV
      __builtin_amdgcn_s_setprio(1);
#pragma unroll
      for (int ksl = 0; ksl < 4; ++ksl) {
        const int b = 8 * (ksl & 1);
        const f32x16& ps = (ksl < 2) ? s0 : s1;
        u32 c0 = cvt_pk_bf16(ps[b + 0], ps[b + 1]);
        u32 c1 = cvt_pk_bf16(ps[b + 2], ps[b + 3]);
        u32 c2 = cvt_pk_bf16(ps[b + 4], ps[b + 5]);
        u32 c3 = cvt_pk_bf16(ps[b + 6], ps[b + 7]);
        pl32_swap(c0, c2);
        pl32_swap(c1, c3);
        union { u32 u[4]; short8 s; } pa;
        pa.u[0] = c0; pa.u[1] = c1; pa.u[2] = c2; pa.u[3] = c3;
        int cl = 2 * ksl + hi;
        int d0r = l & 31, d1r = (l & 31) + 32;
        short8 vf0 = *reinterpret_cast<const short8*>(&vs[d0r * 64 + ((cl ^ (d0r & 7)) * 8)]);
        short8 vf1 = *reinterpret_cast<const short8*>(&vs[d1r * 64 + ((cl ^ (d1r & 7)) * 8)]);
        o0 = __builtin_amdgcn_mfma_f32_32x32x16_bf16(vf0, pa.s, o0, 0, 0, 0);
        o1 = __builtin_amdgcn_mfma_f32_32x32x16_bf16(vf1, pa.s, o1, 0, 0, 0);
      }
      __builtin_amdgcn_s_setprio(0);
    }

    int tmp = ob0; ob0 = ob1; ob1 = ob2; ob2 = ob3; ob3 = tmp;
  }

  // loop has no trailing barrier; epilogue reuses smem -> sync first
  __syncthreads();

  // epilogue: normalize, bounce O^T -> row-major via per-wave LDS, 16B stores
  float inv = 1.0f / l_r;
  u16* Ob = smem + w * 2304;
#pragma unroll
  for (int acc = 0; acc < 2; ++acc) {
    const f32x16& oo = acc ? o1 : o0;
#pragma unroll
    for (int rp = 0; rp < 8; ++rp) {
      u32 pk = cvt_pk_bf16(oo[2 * rp] * inv, oo[2 * rp + 1] * inv);
      int d0 = ((2 * rp) & 3) + 8 * (rp >> 1) + hi4 + 32 * acc;
      *reinterpret_cast<u32*>(&Ob[(l & 31) * 72 + d0]) = pk;
    }
  }
  __syncthreads();
  int qq = l >> 1;
  int chb = (l & 1) * 4;
#pragma unroll
  for (int c2 = 0; c2 < 4; ++c2) {
    uint4v vv = *reinterpret_cast<const uint4v*>(&Ob[qq * 72 + (chb + c2) * 8]);
    *reinterpret_cast<uint4v*>(&AO[qkbase + (size_t)(qw + qq) * D_ + (chb + c2) * 8]) = vv;
  }
}

// ---------------- launch ----------------
extern "C" void kernel_launch(void* const* d_in, const int* in_sizes, int n_in,
                              void* d_out, int out_size, void* d_ws, size_t ws_size,
                              hipStream_t stream) {
  const float* x  = (const float*)d_in[0];
  const float* wq = (const float*)d_in[1];
  const float* wk = (const float*)d_in[2];
  const float* wv = (const float*)d_in[3];
  const float* wo = (const float*)d_in[4];
  const float* bo = (const float*)d_in[5];
  float* out = (float*)d_out;

  char* ws = (char*)d_ws;
  u16* XB   = (u16*)(ws);                       // 16 MiB
  u16* WQKV = (u16*)(ws + (size_t)(16 << 20));  // 6 MiB (wq|wk|wv), then wo
  u16* WOB  = (u16*)(ws + (size_t)(22 << 20));  // 2 MiB
  u16* Qb   = (u16*)(ws + (size_t)(24 << 20));
  u16* Kb   = (u16*)(ws + (size_t)(40 << 20));
  u16* Vt   = (u16*)(ws + (size_t)(56 << 20));  // [bh*64+d][s]
  u16* AO   = (u16*)(ws + (size_t)(72 << 20));

  // one conversion launch: 4096 x-blocks + 2048 weight-blocks
  // wq scale folds DK^-0.5 * log2(e) for exp2-domain softmax
  conv_all<<<6144, 256, 0, stream>>>(x, wq, wk, wv, wo, XB, WQKV,
                                     0.18033688011112042f);

  // QKV: M=8192, N=3072 -> 1536 blocks of 128² (L2-blocked XCD mapping)
  gemm_bt<0><<<1536, 256, 0, stream>>>(
      XB, WQKV, Qb, Kb, Vt, nullptr, nullptr, B_ * S_, 3072, D_, 24);

  attn_fwd<<<dim3(B_ * H_, 8), 512, 0, stream>>>(Qb, Kb, Vt, AO);

  // O-proj: M=8192, N=1024 -> 512 blocks of 128²
  gemm_bt<1><<<512, 256, 0, stream>>>(
      AO, WOB, nullptr, nullptr, nullptr, out, bo, B_ * S_, D_, D_, 8);
}